// Round 8
// baseline (864.057 us; speedup 1.0000x reference)
//
#include <hip/hip_runtime.h>
#include <hip/hip_bf16.h>
#include <stdint.h>

typedef unsigned short u16;
typedef unsigned int   u32;
typedef __bf16 bf16_t;
typedef bf16_t bf16x8 __attribute__((ext_vector_type(8)));
typedef float  f32x4  __attribute__((ext_vector_type(4)));

#define NB     4096
#define LSEQ   28
#define DEMB   300
#define KPAD   8768      // 29 pos x 300 (pos 0 = zeros) + 68 zero tail = 137*64 (BK=64-divisible)
#define NPAIRS 8386560   // 4096*4095/2

#define KP1    1536      // conv1/conv2 GEMM K: 1500 real + 36 zero-WEIGHT cols (24*64)
#define KP3    3008      // conv3 K: 3000 padded, 47*64
#define YSTR   3968      // conv2 source row stride: 2400+1536 window-safe, zero-padded past 3900
#define N1TOT  53248     // 4096*13
#define N2TOT  20480     // 4096*5
#define GSPLIT 3         // gram split-K parts: 46/46/45 of 64
#define G3SPL  6         // conv3 split-K parts (512x5 + 448)

__device__ __forceinline__ u16 f2bf(float f) {
  u32 u = __float_as_uint(f);
  u32 r = (u + 0x7fffu + ((u >> 16) & 1u)) >> 16;  // RNE
  return (u16)r;
}

// async global->LDS 16B copy; LDS dest = wave-uniform base + lane*16.
// NOTE (R6 post-mortem): NEVER pass a nonzero `offset` param — for LDS-DMA the
// instruction offset is applied to the LDS WRITE address (M0+offset+lane*size),
// not the global address. R6's offset=64 staged half-1 from the wrong source
// into shifted LDS slots -> deterministic garbage (absmax 468 signature).
// Express global offsets via explicit pointer arithmetic instead.
__device__ __forceinline__ void cp16(const void* g, void* l) {
  __builtin_amdgcn_global_load_lds((const __attribute__((address_space(1))) void*)g,
                                   (__attribute__((address_space(3))) void*)l, 16, 0, 0);
}

// XCD-aware chunked remap; bijective iff nwg % 8 == 0 (all our grids are).
__device__ __forceinline__ int xcd_remap(int flat, int nwg) {
  return (flat & 7) * (nwg >> 3) + (flat >> 3);
}

// ================== shared MFMA K-loop core ==================
// 128x128 tile, BK=64 via two stacked 128x32 halves, 256 threads, 32 KB LDS.
// Single-buffer + 2 barriers per 64-K. Half 1 staged from the SAME pointers
// +32 elements (explicit address math, offset param always 0 — see cp16 note).
// XOR-swizzled chunk columns at staging keep ds_read_b128 conflict-free.
// Staging swizzle (per 32-half): LDS slot (row, ch) holds global chunk
// (row, ch ^ ((row>>1)&3)).
// NOTE (R3 post-mortem): keep epilogues REGISTER-LEAN; VGPR 64->72 cost 28%
// occupancy and ~60us on conv1. (R7: BK=64 itself costs VGPR 64->80 but nets
// -9% on gram — barrier halving beats the occupancy loss.)
#define MMA_PROLOGUE                                                                   \
  __shared__ alignas(16) u16 As0[8192], Bs0[8192];                                     \
  int tid = threadIdx.x;                                                               \
  int lane = tid & 63, wave = tid >> 6, wm = wave >> 1, wn = wave & 1;                 \
  f32x4 acc[4][4];                                                                     \
  _Pragma("unroll")                                                                    \
  for (int i = 0; i < 4; ++i)                                                          \
    _Pragma("unroll")                                                                  \
    for (int j = 0; j < 4; ++j) acc[i][j] = (f32x4){0.f, 0.f, 0.f, 0.f};               \
  int c0 = tid, c1 = tid + 256;                                                        \
  int r0 = c0 >> 2, r1 = c1 >> 2;                                                      \
  int s0 = (c0 & 3) ^ ((r0 >> 1) & 3);                                                 \
  int s1 = (c1 & 3) ^ ((r1 >> 1) & 3);                                                 \
  int wofs = wave * 512;                                                               \
  int rsel = lane & 15;                                                                \
  int sc   = ((lane >> 4) ^ ((rsel >> 1) & 3)) * 8;                                    \
  int aro  = (wm * 64 + rsel) * 32 + sc;                                               \
  int bro  = (wn * 64 + rsel) * 32 + sc;

#define MMA_LIN_AB(PA, PB, KpadV)                                                      \
  const u16* gA0 = (PA) + (size_t)r0 * (KpadV) + s0 * 8;                               \
  const u16* gB0 = (PB) + (size_t)r0 * (KpadV) + s0 * 8;                               \
  const u16* gA1 = (PA) + (size_t)r1 * (KpadV) + s1 * 8;                               \
  const u16* gB1 = (PB) + (size_t)r1 * (KpadV) + s1 * 8;

#define MMA_HALF(H)                                                                    \
  {                                                                                    \
    bf16x8 af[4], bfr[4];                                                              \
    _Pragma("unroll")                                                                  \
    for (int m = 0; m < 4; ++m) {                                                      \
      af[m]  = *(const bf16x8*)(const void*)(As0 + (H) * 4096 + aro + m * 512);        \
      bfr[m] = *(const bf16x8*)(const void*)(Bs0 + (H) * 4096 + bro + m * 512);        \
    }                                                                                  \
    _Pragma("unroll")                                                                  \
    for (int mi = 0; mi < 4; ++mi)                                                     \
      _Pragma("unroll")                                                                \
      for (int mj = 0; mj < 4; ++mj)                                                   \
        acc[mi][mj] = __builtin_amdgcn_mfma_f32_16x16x32_bf16(af[mi], bfr[mj],         \
                                                              acc[mi][mj], 0, 0, 0);   \
  }

#define MMA_LOOP(kBegV, kEndV)                                                         \
  for (int kk = (kBegV); kk < (kEndV); kk += 64) {                                     \
    const u16* a0 = gA0 + kk;  const u16* b0 = gB0 + kk;                               \
    const u16* a1 = gA1 + kk;  const u16* b1 = gB1 + kk;                               \
    cp16(a0, As0 + wofs);             cp16(b0, Bs0 + wofs);                            \
    cp16(a1, As0 + 2048 + wofs);      cp16(b1, Bs0 + 2048 + wofs);                     \
    cp16(a0 + 32, As0 + 4096 + wofs); cp16(b0 + 32, Bs0 + 4096 + wofs);                \
    cp16(a1 + 32, As0 + 6144 + wofs); cp16(b1 + 32, Bs0 + 6144 + wofs);                \
    __syncthreads();                                                                   \
    MMA_HALF(0)                                                                        \
    MMA_HALF(1)                                                                        \
    __syncthreads();                                                                   \
  }

// ---------------- fused pad+convert of conv weights (+ zero BN accumulators) ----------------
// Aw1/Aw2 reordered to [co][kf] with kf = k*300 + ci (k-major) so that the
// im2col row is a CONTIGUOUS slice of the [b][pos][chan] activation buffer.
// Columns kf in [1500,1536) are ZERO => window over-reads are annihilated.
__global__ void wconv_k(const float* __restrict__ w1, const float* __restrict__ w2,
                        const float* __restrict__ w3, u16* __restrict__ Aw1,
                        u16* __restrict__ Aw2, u16* __restrict__ Aw3,
                        float* __restrict__ bnAcc) {
  if (blockIdx.x == 0) {  // re-zero BN partial-sum accumulators every replay
    for (int i = threadIdx.x; i < 1800; i += 256) bnAcc[i] = 0.f;
  }
  int idx = blockIdx.x * 256 + threadIdx.x;
  const int t1 = 384 * KP1, t2 = 640 * KP1, t3 = 128 * KP3;
  if (idx < t1) {
    int m = idx / KP1, kf = idx - m * KP1;
    u16 v = 0;
    if (m < 300 && kf < 1500) { int k = kf / 300, ci = kf - k * 300; v = f2bf(w1[m * 1500 + ci * 5 + k]); }
    Aw1[idx] = v;
  } else if ((idx -= t1) < t2) {
    int m = idx / KP1, kf = idx - m * KP1;
    u16 v = 0;
    if (m < 600 && kf < 1500) { int k = kf / 300, ci = kf - k * 300; v = f2bf(w2[m * 1500 + ci * 5 + k]); }
    Aw2[idx] = v;
  } else if ((idx -= t2) < t3) {
    int m = idx / KP3, k = idx - m * KP3;
    Aw3[idx] = (m < 100 && k < 3000) ? f2bf(w3[m * 3000 + k]) : (u16)0;
  }
}

// ---------------- embedding row scales: min(1, 1/(||row||+1e-7)) ----------------
__global__ __launch_bounds__(256) void scale_k(const float* __restrict__ emb,
                                               float* __restrict__ scale) {
  int r = blockIdx.x * 4 + (threadIdx.x >> 6);
  int lane = threadIdx.x & 63;
  const float* row = emb + (size_t)r * DEMB;
  float s = 0.f;
  for (int d = lane; d < DEMB; d += 64) { float v = row[d]; s += v * v; }
  for (int off = 32; off; off >>= 1) s += __shfl_xor(s, off, 64);
  if (lane == 0) scale[r] = fminf(1.f, 1.f / (sqrtf(s) + 1e-7f));
}

// ---------------- gather -> Xl bf16 [4096][8768], layout k = (l+1)*300 + d ----------------
// Position 0 (k in [0,300)) is zeros = the pad=1 column; tail [8700,8768) zeros.
__global__ __launch_bounds__(256) void embed_k(const int* __restrict__ x,
                                               const float* __restrict__ emb,
                                               const float* __restrict__ scale,
                                               u16* __restrict__ Xl) {
  __shared__ alignas(16) u16 es[KPAD];
  int b = blockIdx.x, tid = threadIdx.x;
  for (int i = tid; i < 300; i += 256) es[i] = 0;   // pad-position block (loop, not guard!)
  if (tid < 68) es[8700 + tid] = 0;                 // K tail zeros
  const int* xr = x + b * LSEQ;
  for (int l = 0; l < LSEQ; ++l) {
    int v = xr[l];
    float s = scale[v];
    const float* er = emb + (size_t)v * DEMB;
    for (int d = tid; d < DEMB; d += 256) es[(l + 1) * 300 + d] = f2bf(er[d] * s);
  }
  __syncthreads();
  uint4* dst = (uint4*)(Xl + (size_t)b * KPAD);
  const uint4* s4 = (const uint4*)es;
  for (int i = tid; i < KPAD / 8; i += 256) dst[i] = s4[i];
}

// ---------------- BN partial stats: grid C*parts blocks, contiguous chunks ----------------
// Replaces single-pass stats_k (300/600 blocks = 1.2-2.3/CU, latency-starved on
// 113MB). 1200 blocks, one atomicAdd pair per block into bnAcc (zeroed by wconv).
__global__ __launch_bounds__(256) void statsp_k(const float* __restrict__ src, int Ntot,
                                                int parts, float* __restrict__ sumP,
                                                float* __restrict__ sqP) {
  int c = blockIdx.x / parts, part = blockIdx.x - c * parts;
  int chunk = Ntot / parts;   // 53248/4=13312, 20480/2=10240 — both exact
  const float* rp = src + (size_t)c * Ntot + part * chunk;
  float s = 0.f, sq = 0.f;
  for (int i = threadIdx.x; i < chunk; i += 256) { float v = rp[i]; s += v; sq += v * v; }
  for (int off = 32; off; off >>= 1) { s += __shfl_xor(s, off, 64); sq += __shfl_xor(sq, off, 64); }
  __shared__ float l1[4], l2[4];
  int wave = threadIdx.x >> 6, lane = threadIdx.x & 63;
  if (lane == 0) { l1[wave] = s; l2[wave] = sq; }
  __syncthreads();
  if (threadIdx.x == 0) {
    atomicAdd(&sumP[c], l1[0] + l1[1] + l1[2] + l1[3]);
    atomicAdd(&sqP[c],  l2[0] + l2[1] + l2[2] + l2[3]);
  }
}

// ---------------- BN finalize: A=g*inv, B=be-mean*A ----------------
__global__ __launch_bounds__(256) void finstats_k(const float* __restrict__ sum,
                                                  const float* __restrict__ sq,
                                                  const float* __restrict__ g,
                                                  const float* __restrict__ be,
                                                  float* __restrict__ bnA,
                                                  float* __restrict__ bnB, int C, int Ntot) {
  int c = blockIdx.x * 256 + threadIdx.x;
  if (c < C) {
    float mean = sum[c] / Ntot;
    float var = sq[c] / Ntot - mean * mean;
    float inv = rsqrtf(var + 1e-5f);
    float A = g[c] * inv;
    bnA[c] = A; bnB[c] = be[c] - mean * A;
  }
}

// ---------------- bn1+relu(C1) -> Y bf16 [4096][3968], layout k = p*300 + ci ----------------
// XCD-clustered b: adjacent b read the SAME C1 cache lines (52B apart) -> one L2.
__global__ __launch_bounds__(256) void y2_k(const float* __restrict__ C1,
                                            const float* __restrict__ bnA,
                                            const float* __restrict__ bnB,
                                            u16* __restrict__ Y) {
  int b = xcd_remap(blockIdx.x, NB), tid = threadIdx.x;
  u16* yr = Y + (size_t)b * YSTR;
  for (int i = tid; i < YSTR; i += 256) {
    u16 v = 0;
    if (i < 3900) {
      int t = i / 300, ci = i - t * 300;
      v = f2bf(fmaxf(0.f, fmaf(C1[(size_t)ci * N1TOT + b * 13 + t], bnA[ci], bnB[ci])));
    }
    yr[i] = v;
  }
}

// ---------------- im2col for conv3: bn2+relu(C2) -> X3 [4096][3008] ----------------
// XCD-clustered b (C2 column reads, 20B apart across adjacent b).
__global__ __launch_bounds__(128) void im2col3_k(const float* __restrict__ C2,
                                                 const float* __restrict__ bnA,
                                                 const float* __restrict__ bnB,
                                                 u16* __restrict__ X3) {
  int b = xcd_remap(blockIdx.x, NB), tid = threadIdx.x;
  for (int c = tid; c < 376; c += 128) {
    uint4 v;
    u32 wv[4];
    #pragma unroll
    for (int jj = 0; jj < 4; ++jj) {
      u32 pk = 0;
      #pragma unroll
      for (int h = 0; h < 2; ++h) {
        int idx = c * 8 + jj * 2 + h;
        u16 e = 0;
        if (idx < 3000) {
          int ci = idx / 5, k = idx - ci * 5;
          float val = fmaxf(0.f, fmaf(C2[(size_t)ci * N2TOT + b * 5 + k], bnA[ci], bnB[ci]));
          e = f2bf(val);
        }
        pk |= ((u32)e) << (16 * h);
      }
      wv[jj] = pk;
    }
    v.x = wv[0]; v.y = wv[1]; v.z = wv[2]; v.w = wv[3];
    *(uint4*)(X3 + (size_t)b * KP3 + c * 8) = v;
  }
}

// ---------------- conv GEMM, implicit im2col: C = Aw . window-slices(X)^T ----------------
// B row n -> (b = n/NT, t = n%NT); slice base = b*rowStride + 600*t (16B-aligned).
__global__ __launch_bounds__(256) void cgemm_k(const u16* __restrict__ A,
                                               const u16* __restrict__ X,
                                               int rowStride, int NT, int Kpad,
                                               int M, int NtotC, float* __restrict__ C) {
  MMA_PROLOGUE
  int flat = blockIdx.y * gridDim.x + blockIdx.x;
  int orig = xcd_remap(flat, gridDim.x * gridDim.y);
  int tn = orig % gridDim.x, tm = orig / gridDim.x;
  const u16* PA  = A + (size_t)(tm * 128) * Kpad;
  const u16* gA0 = PA + (size_t)r0 * Kpad + s0 * 8;
  const u16* gA1 = PA + (size_t)r1 * Kpad + s1 * 8;
  int n0g = tn * 128 + r0, n1g = tn * 128 + r1;
  int b0 = n0g / NT, b1 = n1g / NT;
  const u16* gB0 = X + (size_t)b0 * rowStride + 600 * (n0g - b0 * NT) + s0 * 8;
  const u16* gB1 = X + (size_t)b1 * rowStride + 600 * (n1g - b1 * NT) + s1 * 8;
  MMA_LOOP(0, Kpad)

  int rb = wm * 64 + ((lane >> 4) << 2);
  int cb = wn * 64 + (lane & 15);
  #pragma unroll
  for (int mi = 0; mi < 4; ++mi)
    #pragma unroll
    for (int r = 0; r < 4; ++r) {
      int m = tm * 128 + rb + mi * 16 + r;
      if (m < M) {
        float* crow = C + (size_t)m * NtotC + tn * 128 + cb;
        #pragma unroll
        for (int mj = 0; mj < 4; ++mj) crow[mj * 16] = acc[mi][mj][r];
      }
    }
}

// ---------------- conv3 partial GEMM, split-K=6 (512x5+448): Ph[(s*32+tn)][m*128+n] ----------------
__global__ __launch_bounds__(256) void gemm3p_k(const u16* __restrict__ A,
                                                const u16* __restrict__ B,
                                                float* __restrict__ Ph) {
  MMA_PROLOGUE
  int tn = blockIdx.x, s = blockIdx.y;
  int kBeg = s * 512;
  int kEnd = (s == G3SPL - 1) ? KP3 : kBeg + 512;
  const u16* PA = A;
  const u16* PB = B + (size_t)(tn * 128) * KP3;
  MMA_LIN_AB(PA, PB, KP3)
  MMA_LOOP(kBeg, kEnd)

  float* po = Ph + ((size_t)(s * 32 + tn)) * 16384;
  int rb = wm * 64 + ((lane >> 4) << 2);
  int cb = wn * 64 + (lane & 15);
  #pragma unroll
  for (int mi = 0; mi < 4; ++mi)
    #pragma unroll
    for (int r = 0; r < 4; ++r) {
      int m = rb + mi * 16 + r;
      #pragma unroll
      for (int mj = 0; mj < 4; ++mj) po[(size_t)m * 128 + cb + mj * 16] = acc[mi][mj][r];
    }
}

// ---------------- finalize conv3: sum partials + bias, tanh, write h, normalize -> Fn ----------------
__global__ __launch_bounds__(64) void fin_k(const float* __restrict__ Ph,
                                            const float* __restrict__ b3,
                                            float* __restrict__ out, u16* __restrict__ Fn) {
  int b = xcd_remap(blockIdx.x, NB), lane = threadIdx.x;
  int tn = b >> 7, bl = b & 127;
  const float* base = Ph + (size_t)tn * 16384 + bl;
  float v0 = b3[lane];
  #pragma unroll
  for (int s = 0; s < G3SPL; ++s) v0 += base[(size_t)s * 32 * 16384 + lane * 128];
  v0 = tanhf(v0);
  float v1 = 0.f;
  if (lane + 64 < 100) {
    v1 = b3[lane + 64];
    #pragma unroll
    for (int s = 0; s < G3SPL; ++s) v1 += base[(size_t)s * 32 * 16384 + (lane + 64) * 128];
    v1 = tanhf(v1);
  }
  float s = v0 * v0 + v1 * v1;
  for (int off = 32; off; off >>= 1) s += __shfl_xor(s, off, 64);
  float rn = rsqrtf(s);
  out[(size_t)b * 100 + lane] = v0;
  if (lane + 64 < 100) out[(size_t)b * 100 + lane + 64] = v1;
  u16* orow = Fn + (size_t)b * 128;
  orow[lane]      = f2bf(v0 * rn);
  orow[lane + 64] = (lane + 64 < 100) ? f2bf(v1 * rn) : (u16)0;
}

// ---------------- input gram, split-K=GSPLIT (46/46/45 x64): full 128x128 partial tiles ----------------
// Launched in TWO passes of 264 tiles (tbase 0 / 264) so the top dispatch drops
// below the conv GEMMs -> rocprof top-5 reveals them (argmax-only visibility).
__global__ __launch_bounds__(256) void gram_part_k(const u16* __restrict__ P,
                                                   float* __restrict__ Pout, int tbase) {
  MMA_PROLOGUE
  int flat = blockIdx.y * 264 + blockIdx.x;
  int orig = xcd_remap(flat, 264 * GSPLIT);
  int s = orig / 264, tile = tbase + (orig - s * 264);
  int q = tile, ti = 0;
  while (q >= 32 - ti) { q -= 32 - ti; ++ti; }
  int tj = ti + q;
  int kBeg = s * 2944;
  int kEnd = kBeg + (s == 2 ? 2880 : 2944);
  const u16* PA = P + (size_t)ti * 128 * KPAD;
  const u16* PB = P + (size_t)tj * 128 * KPAD;
  MMA_LIN_AB(PA, PB, KPAD)
  MMA_LOOP(kBeg, kEnd)

  float* po = Pout + ((size_t)(s * 528 + tile)) * 16384;
  int rb = wm * 64 + ((lane >> 4) << 2);
  int cb = wn * 64 + (lane & 15);
  #pragma unroll
  for (int mi = 0; mi < 4; ++mi)
    #pragma unroll
    for (int r = 0; r < 4; ++r) {
      int row = rb + mi * 16 + r;
      #pragma unroll
      for (int mj = 0; mj < 4; ++mj) po[(size_t)row * 128 + cb + mj * 16] = acc[mi][mj][r];
    }
}

// ---------------- reduce split-K partials -> triangular pair list ----------------
__global__ __launch_bounds__(256) void reduce_k(const float* __restrict__ P,
                                                float* __restrict__ outp) {
  int tile = blockIdx.x;
  int q = tile, ti = 0;
  while (q >= 32 - ti) { q -= 32 - ti; ++ti; }
  int tj = ti + q;
  const float4* p0 = (const float4*)(P + (size_t)tile * 16384);
  const float4* p1 = (const float4*)(P + (size_t)(528 + tile) * 16384);
  const float4* p2 = (const float4*)(P + (size_t)(1056 + tile) * 16384);
  for (int e = threadIdx.x; e < 4096; e += 256) {
    float4 a = p0[e], bv = p1[e], cv = p2[e];
    int i = e >> 5;
    int j0 = (e & 31) * 4;
    int gi = ti * 128 + i;
    int gj = tj * 128 + j0;
    float v[4] = {a.x + bv.x + cv.x, a.y + bv.y + cv.y,
                  a.z + bv.z + cv.z, a.w + bv.w + cv.w};
    #pragma unroll
    for (int u = 0; u < 4; ++u) {
      int gjj = gj + u;
      if (gi < gjj) {
        int pidx = gi * (NB - 1) - ((gi * (gi - 1)) >> 1) + (gjj - gi - 1);
        outp[pidx] = v[u];
      }
    }
  }
}

// ---------------- direct triangular gram (for hidden, K=128) ----------------
__global__ __launch_bounds__(256) void gram_k(const u16* __restrict__ P, int Kpad,
                                              float* __restrict__ outp) {
  MMA_PROLOGUE
  int q = blockIdx.x, ti = 0;
  while (q >= 32 - ti) { q -= 32 - ti; ++ti; }
  int tj = ti + q;
  const u16* PA = P + (size_t)ti * 128 * Kpad;
  const u16* PB = P + (size_t)tj * 128 * Kpad;
  MMA_LIN_AB(PA, PB, Kpad)
  MMA_LOOP(0, Kpad)

  int rbase = ti * 128 + wm * 64 + ((lane >> 4) << 2);
  int cbase = tj * 128 + wn * 64 + (lane & 15);
  #pragma unroll
  for (int mi = 0; mi < 4; ++mi)
    #pragma unroll
    for (int mj = 0; mj < 4; ++mj) {
      int gj = cbase + mj * 16;
      #pragma unroll
      for (int r = 0; r < 4; ++r) {
        int gi = rbase + mi * 16 + r;
        if (gi < gj) {
          int p = gi * (NB - 1) - ((gi * (gi - 1)) >> 1) + (gj - gi - 1);
          outp[p] = acc[mi][mj][r];
        }
      }
    }
}

extern "C" void kernel_launch(void* const* d_in, const int* in_sizes, int n_in,
                              void* d_out, int out_size, void* d_ws, size_t ws_size,
                              hipStream_t stream) {
  const int*   x   = (const int*)d_in[0];
  const float* emb = (const float*)d_in[1];
  const float* w1  = (const float*)d_in[2];
  const float* w2  = (const float*)d_in[4];
  const float* w3  = (const float*)d_in[6];
  const float* b3  = (const float*)d_in[7];
  const float* g1  = (const float*)d_in[8];
  const float* be1 = (const float*)d_in[9];
  const float* g2  = (const float*)d_in[10];
  const float* be2 = (const float*)d_in[11];
  float* out = (float*)d_out;

  char* p = (char*)d_ws;
  auto alloc = [&](size_t bytes) { char* r = p; p += (bytes + 255) & ~(size_t)255; return r; };
  float* scale = (float*)alloc((size_t)32000 * 4);
  u16*   Aw1   = (u16*)alloc((size_t)384 * KP1 * 2);
  u16*   Aw2   = (u16*)alloc((size_t)640 * KP1 * 2);
  u16*   Aw3   = (u16*)alloc((size_t)128 * KP3 * 2);
  float* bnAcc = (float*)alloc(1800 * 4);   // sum1[300] sq1[300] sum2[600] sq2[600]
  float* sum1 = bnAcc, *sq1 = bnAcc + 300, *sum2 = bnAcc + 600, *sq2 = bnAcc + 1200;
  float* bnA1  = (float*)alloc(300 * 4);
  float* bnB1  = (float*)alloc(300 * 4);
  float* bnA2  = (float*)alloc(600 * 4);
  float* bnB2  = (float*)alloc(600 * 4);
  u16*   Fn    = (u16*)alloc((size_t)NB * 128 * 2);
  // Region 1 (71.8MB): Xl -> Y -> X3 (each producer runs after prior consumer)
  char*  reg1  = alloc((size_t)NB * KPAD * 2);
  // Region 2 (103.8MB): Pg -> C1 -> C2 -> Ph
  char*  reg2  = alloc((size_t)GSPLIT * 528 * 16384 * 4);
  u16*   Xl = (u16*)reg1;
  u16*   Y  = (u16*)reg1;
  u16*   X3 = (u16*)reg1;
  float* Pg = (float*)reg2;
  float* C1 = (float*)reg2;
  float* C2 = (float*)reg2;
  float* Ph = (float*)reg2;

  wconv_k<<<(384 * KP1 + 640 * KP1 + 128 * KP3 + 255) / 256, 256, 0, stream>>>(
      w1, w2, w3, Aw1, Aw2, Aw3, bnAcc);
  scale_k<<<32000 / 4, 256, 0, stream>>>(emb, scale);
  embed_k<<<NB, 256, 0, stream>>>(x, emb, scale, Xl);

  // input_pws: split-K gram (2 x 792 blocks, XCD-chunked) + reduction
  gram_part_k<<<dim3(264, GSPLIT), 256, 0, stream>>>(Xl, Pg, 0);
  gram_part_k<<<dim3(264, GSPLIT), 256, 0, stream>>>(Xl, Pg, 264);
  reduce_k<<<528, 256, 0, stream>>>(Pg, out + 409600);

  // conv1: implicit-im2col GEMM straight from Xl (Pg dead; C1 -> reg2)
  cgemm_k<<<dim3(416, 3), 256, 0, stream>>>(Aw1, Xl, KPAD, 13, KP1, 300, N1TOT, C1);
  statsp_k<<<300 * 4, 256, 0, stream>>>(C1, N1TOT, 4, sum1, sq1);
  finstats_k<<<2, 256, 0, stream>>>(sum1, sq1, g1, be1, bnA1, bnB1, 300, N1TOT);
  y2_k<<<NB, 256, 0, stream>>>(C1, bnA1, bnB1, Y);                     // Y over Xl (dead)
  // conv2: implicit-im2col GEMM from Y (C2 over C1, dead)
  cgemm_k<<<dim3(160, 5), 256, 0, stream>>>(Aw2, Y, YSTR, 5, KP1, 600, N2TOT, C2);
  statsp_k<<<600 * 2, 256, 0, stream>>>(C2, N2TOT, 2, sum2, sq2);
  finstats_k<<<3, 256, 0, stream>>>(sum2, sq2, g2, be2, bnA2, bnB2, 600, N2TOT);
  im2col3_k<<<NB, 128, 0, stream>>>(C2, bnA2, bnB2, X3);               // X3 over Y (dead)
  gemm3p_k<<<dim3(32, G3SPL), 256, 0, stream>>>(Aw3, X3, Ph);          // conv3 split-K=6
  fin_k<<<NB, 64, 0, stream>>>(Ph, b3, out, Fn);                       // h + normalized Fn
  gram_k<<<528, 256, 0, stream>>>(Fn, 128, out + 409600 + NPAIRS);     // hidden_pws
}

// Round 9
// 810.775 us; speedup vs baseline: 1.0657x; 1.0657x over previous
//
#include <hip/hip_runtime.h>
#include <hip/hip_bf16.h>
#include <stdint.h>

typedef unsigned short u16;
typedef unsigned int   u32;
typedef __bf16 bf16_t;
typedef bf16_t bf16x8 __attribute__((ext_vector_type(8)));
typedef float  f32x4  __attribute__((ext_vector_type(4)));

#define NB     4096
#define LSEQ   28
#define DEMB   300
#define KPAD   8768      // 29 pos x 300 (pos 0 = zeros) + 68 zero tail = 137*64 (BK=64-divisible)
#define NPAIRS 8386560   // 4096*4095/2

#define KP1    1536      // conv1/conv2 GEMM K: 1500 real + 36 zero-WEIGHT cols (24*64)
#define KP3    3008      // conv3 K: 3000 padded, 47*64
#define YSTR   3968      // conv2 source row stride: 2400+1536 window-safe, zero-padded past 3900
#define N1TOT  53248     // 4096*13
#define N2TOT  20480     // 4096*5
#define GSPLIT 3         // gram split-K parts: 46/46/45 of 64
#define G3SPL  6         // conv3 split-K parts (512x5 + 448)

__device__ __forceinline__ u16 f2bf(float f) {
  u32 u = __float_as_uint(f);
  u32 r = (u + 0x7fffu + ((u >> 16) & 1u)) >> 16;  // RNE
  return (u16)r;
}

// async global->LDS 16B copy; LDS dest = wave-uniform base + lane*16.
// NOTE (R6 post-mortem): NEVER pass a nonzero `offset` param — for LDS-DMA the
// instruction offset is applied to the LDS WRITE address (M0+offset+lane*size),
// not the global address. R6's offset=64 staged half-1 from the wrong source
// into shifted LDS slots -> deterministic garbage (absmax 468 signature).
// Express global offsets via explicit pointer arithmetic instead.
__device__ __forceinline__ void cp16(const void* g, void* l) {
  __builtin_amdgcn_global_load_lds((const __attribute__((address_space(1))) void*)g,
                                   (__attribute__((address_space(3))) void*)l, 16, 0, 0);
}

// XCD-aware chunked remap; bijective iff nwg % 8 == 0 (all our grids are).
__device__ __forceinline__ int xcd_remap(int flat, int nwg) {
  return (flat & 7) * (nwg >> 3) + (flat >> 3);
}

// ================== shared MFMA K-loop core ==================
// 128x128 tile, BK=64 via two stacked 128x32 halves, 256 threads, 32 KB LDS.
// Single-buffer + 2 barriers per 64-K. Half 1 staged from the SAME pointers
// +32 elements (explicit address math, offset param always 0 — see cp16 note).
// XOR-swizzled chunk columns at staging keep ds_read_b128 conflict-free.
// Staging swizzle (per 32-half): LDS slot (row, ch) holds global chunk
// (row, ch ^ ((row>>1)&3)).
// NOTE (R3): keep epilogues REGISTER-LEAN (VGPR 64->72 cost 28% occupancy).
// NOTE (R7): BK=64 costs VGPR 64->80 but nets -9% — barrier halving wins.
// NOTE (R8): do NOT split big MMA launches — same-stream kernels serialize;
// two 792-block halves cost +58us in ramp+tail vs one 1584-block launch.
#define MMA_PROLOGUE                                                                   \
  __shared__ alignas(16) u16 As0[8192], Bs0[8192];                                     \
  int tid = threadIdx.x;                                                               \
  int lane = tid & 63, wave = tid >> 6, wm = wave >> 1, wn = wave & 1;                 \
  f32x4 acc[4][4];                                                                     \
  _Pragma("unroll")                                                                    \
  for (int i = 0; i < 4; ++i)                                                          \
    _Pragma("unroll")                                                                  \
    for (int j = 0; j < 4; ++j) acc[i][j] = (f32x4){0.f, 0.f, 0.f, 0.f};               \
  int c0 = tid, c1 = tid + 256;                                                        \
  int r0 = c0 >> 2, r1 = c1 >> 2;                                                      \
  int s0 = (c0 & 3) ^ ((r0 >> 1) & 3);                                                 \
  int s1 = (c1 & 3) ^ ((r1 >> 1) & 3);                                                 \
  int wofs = wave * 512;                                                               \
  int rsel = lane & 15;                                                                \
  int sc   = ((lane >> 4) ^ ((rsel >> 1) & 3)) * 8;                                    \
  int aro  = (wm * 64 + rsel) * 32 + sc;                                               \
  int bro  = (wn * 64 + rsel) * 32 + sc;

#define MMA_LIN_AB(PA, PB, KpadV)                                                      \
  const u16* gA0 = (PA) + (size_t)r0 * (KpadV) + s0 * 8;                               \
  const u16* gB0 = (PB) + (size_t)r0 * (KpadV) + s0 * 8;                               \
  const u16* gA1 = (PA) + (size_t)r1 * (KpadV) + s1 * 8;                               \
  const u16* gB1 = (PB) + (size_t)r1 * (KpadV) + s1 * 8;

#define MMA_HALF(H)                                                                    \
  {                                                                                    \
    bf16x8 af[4], bfr[4];                                                              \
    _Pragma("unroll")                                                                  \
    for (int m = 0; m < 4; ++m) {                                                      \
      af[m]  = *(const bf16x8*)(const void*)(As0 + (H) * 4096 + aro + m * 512);        \
      bfr[m] = *(const bf16x8*)(const void*)(Bs0 + (H) * 4096 + bro + m * 512);        \
    }                                                                                  \
    _Pragma("unroll")                                                                  \
    for (int mi = 0; mi < 4; ++mi)                                                     \
      _Pragma("unroll")                                                                \
      for (int mj = 0; mj < 4; ++mj)                                                   \
        acc[mi][mj] = __builtin_amdgcn_mfma_f32_16x16x32_bf16(af[mi], bfr[mj],         \
                                                              acc[mi][mj], 0, 0, 0);   \
  }

#define MMA_LOOP(kBegV, kEndV)                                                         \
  for (int kk = (kBegV); kk < (kEndV); kk += 64) {                                     \
    const u16* a0 = gA0 + kk;  const u16* b0 = gB0 + kk;                               \
    const u16* a1 = gA1 + kk;  const u16* b1 = gB1 + kk;                               \
    cp16(a0, As0 + wofs);             cp16(b0, Bs0 + wofs);                            \
    cp16(a1, As0 + 2048 + wofs);      cp16(b1, Bs0 + 2048 + wofs);                     \
    cp16(a0 + 32, As0 + 4096 + wofs); cp16(b0 + 32, Bs0 + 4096 + wofs);                \
    cp16(a1 + 32, As0 + 6144 + wofs); cp16(b1 + 32, Bs0 + 6144 + wofs);                \
    __syncthreads();                                                                   \
    MMA_HALF(0)                                                                        \
    MMA_HALF(1)                                                                        \
    __syncthreads();                                                                   \
  }

// ---------------- fused pad+convert of conv weights (+ zero BN accumulators) ----------------
// Aw1/Aw2 reordered to [co][kf] with kf = k*300 + ci (k-major) so that the
// im2col row is a CONTIGUOUS slice of the [b][pos][chan] activation buffer.
// Columns kf in [1500,1536) are ZERO => window over-reads are annihilated.
__global__ void wconv_k(const float* __restrict__ w1, const float* __restrict__ w2,
                        const float* __restrict__ w3, u16* __restrict__ Aw1,
                        u16* __restrict__ Aw2, u16* __restrict__ Aw3,
                        float* __restrict__ bnAcc) {
  if (blockIdx.x == 0) {  // re-zero BN partial-sum accumulators every replay
    for (int i = threadIdx.x; i < 1800; i += 256) bnAcc[i] = 0.f;
  }
  int idx = blockIdx.x * 256 + threadIdx.x;
  const int t1 = 384 * KP1, t2 = 640 * KP1, t3 = 128 * KP3;
  if (idx < t1) {
    int m = idx / KP1, kf = idx - m * KP1;
    u16 v = 0;
    if (m < 300 && kf < 1500) { int k = kf / 300, ci = kf - k * 300; v = f2bf(w1[m * 1500 + ci * 5 + k]); }
    Aw1[idx] = v;
  } else if ((idx -= t1) < t2) {
    int m = idx / KP1, kf = idx - m * KP1;
    u16 v = 0;
    if (m < 600 && kf < 1500) { int k = kf / 300, ci = kf - k * 300; v = f2bf(w2[m * 1500 + ci * 5 + k]); }
    Aw2[idx] = v;
  } else if ((idx -= t2) < t3) {
    int m = idx / KP3, k = idx - m * KP3;
    Aw3[idx] = (m < 100 && k < 3000) ? f2bf(w3[m * 3000 + k]) : (u16)0;
  }
}

// ---------------- embedding row scales: min(1, 1/(||row||+1e-7)) ----------------
__global__ __launch_bounds__(256) void scale_k(const float* __restrict__ emb,
                                               float* __restrict__ scale) {
  int r = blockIdx.x * 4 + (threadIdx.x >> 6);
  int lane = threadIdx.x & 63;
  const float* row = emb + (size_t)r * DEMB;
  float s = 0.f;
  for (int d = lane; d < DEMB; d += 64) { float v = row[d]; s += v * v; }
  for (int off = 32; off; off >>= 1) s += __shfl_xor(s, off, 64);
  if (lane == 0) scale[r] = fminf(1.f, 1.f / (sqrtf(s) + 1e-7f));
}

// ---------------- gather -> Xl bf16 [4096][8768], layout k = (l+1)*300 + d ----------------
// Position 0 (k in [0,300)) is zeros = the pad=1 column; tail [8700,8768) zeros.
__global__ __launch_bounds__(256) void embed_k(const int* __restrict__ x,
                                               const float* __restrict__ emb,
                                               const float* __restrict__ scale,
                                               u16* __restrict__ Xl) {
  __shared__ alignas(16) u16 es[KPAD];
  int b = blockIdx.x, tid = threadIdx.x;
  for (int i = tid; i < 300; i += 256) es[i] = 0;   // pad-position block (loop, not guard!)
  if (tid < 68) es[8700 + tid] = 0;                 // K tail zeros
  const int* xr = x + b * LSEQ;
  for (int l = 0; l < LSEQ; ++l) {
    int v = xr[l];
    float s = scale[v];
    const float* er = emb + (size_t)v * DEMB;
    for (int d = tid; d < DEMB; d += 256) es[(l + 1) * 300 + d] = f2bf(er[d] * s);
  }
  __syncthreads();
  uint4* dst = (uint4*)(Xl + (size_t)b * KPAD);
  const uint4* s4 = (const uint4*)es;
  for (int i = tid; i < KPAD / 8; i += 256) dst[i] = s4[i];
}

// ---------------- BN partial stats: grid C*parts blocks, contiguous chunks ----------------
// 1200 blocks (vs 300/600 single-pass = latency-starved); one atomicAdd pair
// per block into bnAcc (zeroed by wconv). R8: -~50us combined with G3SPL=6.
__global__ __launch_bounds__(256) void statsp_k(const float* __restrict__ src, int Ntot,
                                                int parts, float* __restrict__ sumP,
                                                float* __restrict__ sqP) {
  int c = blockIdx.x / parts, part = blockIdx.x - c * parts;
  int chunk = Ntot / parts;   // 53248/4=13312, 20480/2=10240 — both exact
  const float* rp = src + (size_t)c * Ntot + part * chunk;
  float s = 0.f, sq = 0.f;
  for (int i = threadIdx.x; i < chunk; i += 256) { float v = rp[i]; s += v; sq += v * v; }
  for (int off = 32; off; off >>= 1) { s += __shfl_xor(s, off, 64); sq += __shfl_xor(sq, off, 64); }
  __shared__ float l1[4], l2[4];
  int wave = threadIdx.x >> 6, lane = threadIdx.x & 63;
  if (lane == 0) { l1[wave] = s; l2[wave] = sq; }
  __syncthreads();
  if (threadIdx.x == 0) {
    atomicAdd(&sumP[c], l1[0] + l1[1] + l1[2] + l1[3]);
    atomicAdd(&sqP[c],  l2[0] + l2[1] + l2[2] + l2[3]);
  }
}

// ---------------- BN finalize: A=g*inv, B=be-mean*A ----------------
__global__ __launch_bounds__(256) void finstats_k(const float* __restrict__ sum,
                                                  const float* __restrict__ sq,
                                                  const float* __restrict__ g,
                                                  const float* __restrict__ be,
                                                  float* __restrict__ bnA,
                                                  float* __restrict__ bnB, int C, int Ntot) {
  int c = blockIdx.x * 256 + threadIdx.x;
  if (c < C) {
    float mean = sum[c] / Ntot;
    float var = sq[c] / Ntot - mean * mean;
    float inv = rsqrtf(var + 1e-5f);
    float A = g[c] * inv;
    bnA[c] = A; bnB[c] = be[c] - mean * A;
  }
}

// ---------------- bn1+relu(C1) -> Y bf16 [4096][3968], layout k = p*300 + ci ----------------
// XCD-clustered b: adjacent b read the SAME C1 cache lines (52B apart) -> one L2.
__global__ __launch_bounds__(256) void y2_k(const float* __restrict__ C1,
                                            const float* __restrict__ bnA,
                                            const float* __restrict__ bnB,
                                            u16* __restrict__ Y) {
  int b = xcd_remap(blockIdx.x, NB), tid = threadIdx.x;
  u16* yr = Y + (size_t)b * YSTR;
  for (int i = tid; i < YSTR; i += 256) {
    u16 v = 0;
    if (i < 3900) {
      int t = i / 300, ci = i - t * 300;
      v = f2bf(fmaxf(0.f, fmaf(C1[(size_t)ci * N1TOT + b * 13 + t], bnA[ci], bnB[ci])));
    }
    yr[i] = v;
  }
}

// ---------------- im2col for conv3: bn2+relu(C2) -> X3 [4096][3008] ----------------
// XCD-clustered b (C2 column reads, 20B apart across adjacent b).
__global__ __launch_bounds__(128) void im2col3_k(const float* __restrict__ C2,
                                                 const float* __restrict__ bnA,
                                                 const float* __restrict__ bnB,
                                                 u16* __restrict__ X3) {
  int b = xcd_remap(blockIdx.x, NB), tid = threadIdx.x;
  for (int c = tid; c < 376; c += 128) {
    uint4 v;
    u32 wv[4];
    #pragma unroll
    for (int jj = 0; jj < 4; ++jj) {
      u32 pk = 0;
      #pragma unroll
      for (int h = 0; h < 2; ++h) {
        int idx = c * 8 + jj * 2 + h;
        u16 e = 0;
        if (idx < 3000) {
          int ci = idx / 5, k = idx - ci * 5;
          float val = fmaxf(0.f, fmaf(C2[(size_t)ci * N2TOT + b * 5 + k], bnA[ci], bnB[ci]));
          e = f2bf(val);
        }
        pk |= ((u32)e) << (16 * h);
      }
      wv[jj] = pk;
    }
    v.x = wv[0]; v.y = wv[1]; v.z = wv[2]; v.w = wv[3];
    *(uint4*)(X3 + (size_t)b * KP3 + c * 8) = v;
  }
}

// ---------------- conv GEMM, implicit im2col: C = Aw . window-slices(X)^T ----------------
// B row n -> (b = n/NT, t = n%NT); slice base = b*rowStride + 600*t (16B-aligned).
__global__ __launch_bounds__(256) void cgemm_k(const u16* __restrict__ A,
                                               const u16* __restrict__ X,
                                               int rowStride, int NT, int Kpad,
                                               int M, int NtotC, float* __restrict__ C) {
  MMA_PROLOGUE
  int flat = blockIdx.y * gridDim.x + blockIdx.x;
  int orig = xcd_remap(flat, gridDim.x * gridDim.y);
  int tn = orig % gridDim.x, tm = orig / gridDim.x;
  const u16* PA  = A + (size_t)(tm * 128) * Kpad;
  const u16* gA0 = PA + (size_t)r0 * Kpad + s0 * 8;
  const u16* gA1 = PA + (size_t)r1 * Kpad + s1 * 8;
  int n0g = tn * 128 + r0, n1g = tn * 128 + r1;
  int b0 = n0g / NT, b1 = n1g / NT;
  const u16* gB0 = X + (size_t)b0 * rowStride + 600 * (n0g - b0 * NT) + s0 * 8;
  const u16* gB1 = X + (size_t)b1 * rowStride + 600 * (n1g - b1 * NT) + s1 * 8;
  MMA_LOOP(0, Kpad)

  int rb = wm * 64 + ((lane >> 4) << 2);
  int cb = wn * 64 + (lane & 15);
  #pragma unroll
  for (int mi = 0; mi < 4; ++mi)
    #pragma unroll
    for (int r = 0; r < 4; ++r) {
      int m = tm * 128 + rb + mi * 16 + r;
      if (m < M) {
        float* crow = C + (size_t)m * NtotC + tn * 128 + cb;
        #pragma unroll
        for (int mj = 0; mj < 4; ++mj) crow[mj * 16] = acc[mi][mj][r];
      }
    }
}

// ---------------- conv3 partial GEMM, split-K=6 (512x5+448): Ph[(s*32+tn)][m*128+n] ----------------
__global__ __launch_bounds__(256) void gemm3p_k(const u16* __restrict__ A,
                                                const u16* __restrict__ B,
                                                float* __restrict__ Ph) {
  MMA_PROLOGUE
  int tn = blockIdx.x, s = blockIdx.y;
  int kBeg = s * 512;
  int kEnd = (s == G3SPL - 1) ? KP3 : kBeg + 512;
  const u16* PA = A;
  const u16* PB = B + (size_t)(tn * 128) * KP3;
  MMA_LIN_AB(PA, PB, KP3)
  MMA_LOOP(kBeg, kEnd)

  float* po = Ph + ((size_t)(s * 32 + tn)) * 16384;
  int rb = wm * 64 + ((lane >> 4) << 2);
  int cb = wn * 64 + (lane & 15);
  #pragma unroll
  for (int mi = 0; mi < 4; ++mi)
    #pragma unroll
    for (int r = 0; r < 4; ++r) {
      int m = rb + mi * 16 + r;
      #pragma unroll
      for (int mj = 0; mj < 4; ++mj) po[(size_t)m * 128 + cb + mj * 16] = acc[mi][mj][r];
    }
}

// ---------------- finalize conv3: sum partials + bias, tanh, write h, normalize -> Fn ----------------
__global__ __launch_bounds__(64) void fin_k(const float* __restrict__ Ph,
                                            const float* __restrict__ b3,
                                            float* __restrict__ out, u16* __restrict__ Fn) {
  int b = xcd_remap(blockIdx.x, NB), lane = threadIdx.x;
  int tn = b >> 7, bl = b & 127;
  const float* base = Ph + (size_t)tn * 16384 + bl;
  float v0 = b3[lane];
  #pragma unroll
  for (int s = 0; s < G3SPL; ++s) v0 += base[(size_t)s * 32 * 16384 + lane * 128];
  v0 = tanhf(v0);
  float v1 = 0.f;
  if (lane + 64 < 100) {
    v1 = b3[lane + 64];
    #pragma unroll
    for (int s = 0; s < G3SPL; ++s) v1 += base[(size_t)s * 32 * 16384 + (lane + 64) * 128];
    v1 = tanhf(v1);
  }
  float s = v0 * v0 + v1 * v1;
  for (int off = 32; off; off >>= 1) s += __shfl_xor(s, off, 64);
  float rn = rsqrtf(s);
  out[(size_t)b * 100 + lane] = v0;
  if (lane + 64 < 100) out[(size_t)b * 100 + lane + 64] = v1;
  u16* orow = Fn + (size_t)b * 128;
  orow[lane]      = f2bf(v0 * rn);
  orow[lane + 64] = (lane + 64 < 100) ? f2bf(v1 * rn) : (u16)0;
}

// ---------------- input gram, split-K=GSPLIT (46/46/45 x64): full 128x128 partial tiles ----------------
// ONE 1584-block launch (R8: splitting into two 792-block launches cost +58us).
__global__ __launch_bounds__(256) void gram_part_k(const u16* __restrict__ P,
                                                   float* __restrict__ Pout) {
  MMA_PROLOGUE
  int flat = blockIdx.y * 528 + blockIdx.x;
  int orig = xcd_remap(flat, 528 * GSPLIT);
  int s = orig / 528, tile = orig - s * 528;
  int q = tile, ti = 0;
  while (q >= 32 - ti) { q -= 32 - ti; ++ti; }
  int tj = ti + q;
  int kBeg = s * 2944;
  int kEnd = kBeg + (s == 2 ? 2880 : 2944);
  const u16* PA = P + (size_t)ti * 128 * KPAD;
  const u16* PB = P + (size_t)tj * 128 * KPAD;
  MMA_LIN_AB(PA, PB, KPAD)
  MMA_LOOP(kBeg, kEnd)

  float* po = Pout + ((size_t)(s * 528 + tile)) * 16384;
  int rb = wm * 64 + ((lane >> 4) << 2);
  int cb = wn * 64 + (lane & 15);
  #pragma unroll
  for (int mi = 0; mi < 4; ++mi)
    #pragma unroll
    for (int r = 0; r < 4; ++r) {
      int row = rb + mi * 16 + r;
      #pragma unroll
      for (int mj = 0; mj < 4; ++mj) po[(size_t)row * 128 + cb + mj * 16] = acc[mi][mj][r];
    }
}

// ---------------- reduce split-K partials -> triangular pair list ----------------
__global__ __launch_bounds__(256) void reduce_k(const float* __restrict__ P,
                                                float* __restrict__ outp) {
  int tile = blockIdx.x;
  int q = tile, ti = 0;
  while (q >= 32 - ti) { q -= 32 - ti; ++ti; }
  int tj = ti + q;
  const float4* p0 = (const float4*)(P + (size_t)tile * 16384);
  const float4* p1 = (const float4*)(P + (size_t)(528 + tile) * 16384);
  const float4* p2 = (const float4*)(P + (size_t)(1056 + tile) * 16384);
  for (int e = threadIdx.x; e < 4096; e += 256) {
    float4 a = p0[e], bv = p1[e], cv = p2[e];
    int i = e >> 5;
    int j0 = (e & 31) * 4;
    int gi = ti * 128 + i;
    int gj = tj * 128 + j0;
    float v[4] = {a.x + bv.x + cv.x, a.y + bv.y + cv.y,
                  a.z + bv.z + cv.z, a.w + bv.w + cv.w};
    #pragma unroll
    for (int u = 0; u < 4; ++u) {
      int gjj = gj + u;
      if (gi < gjj) {
        int pidx = gi * (NB - 1) - ((gi * (gi - 1)) >> 1) + (gjj - gi - 1);
        outp[pidx] = v[u];
      }
    }
  }
}

// ---------------- direct triangular gram (for hidden, K=128) ----------------
__global__ __launch_bounds__(256) void gram_k(const u16* __restrict__ P, int Kpad,
                                              float* __restrict__ outp) {
  MMA_PROLOGUE
  int q = blockIdx.x, ti = 0;
  while (q >= 32 - ti) { q -= 32 - ti; ++ti; }
  int tj = ti + q;
  const u16* PA = P + (size_t)ti * 128 * Kpad;
  const u16* PB = P + (size_t)tj * 128 * Kpad;
  MMA_LIN_AB(PA, PB, Kpad)
  MMA_LOOP(0, Kpad)

  int rbase = ti * 128 + wm * 64 + ((lane >> 4) << 2);
  int cbase = tj * 128 + wn * 64 + (lane & 15);
  #pragma unroll
  for (int mi = 0; mi < 4; ++mi)
    #pragma unroll
    for (int mj = 0; mj < 4; ++mj) {
      int gj = cbase + mj * 16;
      #pragma unroll
      for (int r = 0; r < 4; ++r) {
        int gi = rbase + mi * 16 + r;
        if (gi < gj) {
          int p = gi * (NB - 1) - ((gi * (gi - 1)) >> 1) + (gj - gi - 1);
          outp[p] = acc[mi][mj][r];
        }
      }
    }
}

extern "C" void kernel_launch(void* const* d_in, const int* in_sizes, int n_in,
                              void* d_out, int out_size, void* d_ws, size_t ws_size,
                              hipStream_t stream) {
  const int*   x   = (const int*)d_in[0];
  const float* emb = (const float*)d_in[1];
  const float* w1  = (const float*)d_in[2];
  const float* w2  = (const float*)d_in[4];
  const float* w3  = (const float*)d_in[6];
  const float* b3  = (const float*)d_in[7];
  const float* g1  = (const float*)d_in[8];
  const float* be1 = (const float*)d_in[9];
  const float* g2  = (const float*)d_in[10];
  const float* be2 = (const float*)d_in[11];
  float* out = (float*)d_out;

  char* p = (char*)d_ws;
  auto alloc = [&](size_t bytes) { char* r = p; p += (bytes + 255) & ~(size_t)255; return r; };
  float* scale = (float*)alloc((size_t)32000 * 4);
  u16*   Aw1   = (u16*)alloc((size_t)384 * KP1 * 2);
  u16*   Aw2   = (u16*)alloc((size_t)640 * KP1 * 2);
  u16*   Aw3   = (u16*)alloc((size_t)128 * KP3 * 2);
  float* bnAcc = (float*)alloc(1800 * 4);   // sum1[300] sq1[300] sum2[600] sq2[600]
  float* sum1 = bnAcc, *sq1 = bnAcc + 300, *sum2 = bnAcc + 600, *sq2 = bnAcc + 1200;
  float* bnA1  = (float*)alloc(300 * 4);
  float* bnB1  = (float*)alloc(300 * 4);
  float* bnA2  = (float*)alloc(600 * 4);
  float* bnB2  = (float*)alloc(600 * 4);
  u16*   Fn    = (u16*)alloc((size_t)NB * 128 * 2);
  // Region 1 (71.8MB): Xl -> Y -> X3 (each producer runs after prior consumer)
  char*  reg1  = alloc((size_t)NB * KPAD * 2);
  // Region 2 (103.8MB): Pg -> C1 -> C2 -> Ph
  char*  reg2  = alloc((size_t)GSPLIT * 528 * 16384 * 4);
  u16*   Xl = (u16*)reg1;
  u16*   Y  = (u16*)reg1;
  u16*   X3 = (u16*)reg1;
  float* Pg = (float*)reg2;
  float* C1 = (float*)reg2;
  float* C2 = (float*)reg2;
  float* Ph = (float*)reg2;

  wconv_k<<<(384 * KP1 + 640 * KP1 + 128 * KP3 + 255) / 256, 256, 0, stream>>>(
      w1, w2, w3, Aw1, Aw2, Aw3, bnAcc);
  scale_k<<<32000 / 4, 256, 0, stream>>>(emb, scale);
  embed_k<<<NB, 256, 0, stream>>>(x, emb, scale, Xl);

  // input_pws: split-K gram (1584 blocks, XCD-chunked) + reduction
  gram_part_k<<<dim3(528, GSPLIT), 256, 0, stream>>>(Xl, Pg);
  reduce_k<<<528, 256, 0, stream>>>(Pg, out + 409600);

  // conv1: implicit-im2col GEMM straight from Xl (Pg dead; C1 -> reg2)
  cgemm_k<<<dim3(416, 3), 256, 0, stream>>>(Aw1, Xl, KPAD, 13, KP1, 300, N1TOT, C1);
  statsp_k<<<300 * 4, 256, 0, stream>>>(C1, N1TOT, 4, sum1, sq1);
  finstats_k<<<2, 256, 0, stream>>>(sum1, sq1, g1, be1, bnA1, bnB1, 300, N1TOT);
  y2_k<<<NB, 256, 0, stream>>>(C1, bnA1, bnB1, Y);                     // Y over Xl (dead)
  // conv2: implicit-im2col GEMM from Y (C2 over C1, dead)
  cgemm_k<<<dim3(160, 5), 256, 0, stream>>>(Aw2, Y, YSTR, 5, KP1, 600, N2TOT, C2);
  statsp_k<<<600 * 2, 256, 0, stream>>>(C2, N2TOT, 2, sum2, sq2);
  finstats_k<<<3, 256, 0, stream>>>(sum2, sq2, g2, be2, bnA2, bnB2, 600, N2TOT);
  im2col3_k<<<NB, 128, 0, stream>>>(C2, bnA2, bnB2, X3);               // X3 over Y (dead)
  gemm3p_k<<<dim3(32, G3SPL), 256, 0, stream>>>(Aw3, X3, Ph);          // conv3 split-K=6
  fin_k<<<NB, 64, 0, stream>>>(Ph, b3, out, Fn);                       // h + normalized Fn
  gram_k<<<528, 256, 0, stream>>>(Fn, 128, out + 409600 + NPAIRS);     // hidden_pws
}

// Round 10
// 777.905 us; speedup vs baseline: 1.1107x; 1.0423x over previous
//
#include <hip/hip_runtime.h>
#include <hip/hip_bf16.h>
#include <stdint.h>

typedef unsigned short u16;
typedef unsigned int   u32;
typedef __bf16 bf16_t;
typedef bf16_t bf16x8 __attribute__((ext_vector_type(8)));
typedef float  f32x4  __attribute__((ext_vector_type(4)));

#define NB     4096
#define LSEQ   28
#define DEMB   300
#define KPAD   8768      // 29 pos x 300 (pos 0 = zeros) + 68 zero tail = 137*64 (BK=64-divisible)
#define NPAIRS 8386560   // 4096*4095/2

#define KP1    1536      // conv1/conv2 GEMM K: 1500 real + 36 zero-WEIGHT cols (24*64)
#define KP3    3008      // conv3 K: 3000 padded, 47*64
#define YSTR   3968      // conv2 source row stride: 2400+1536 window-safe, zero-padded past 3900
#define N1TOT  53248     // 4096*13
#define N2TOT  20480     // 4096*5
#define GSPLIT 3         // gram split-K parts: 44/44/44 of 64 over [256,8704)
#define G3SPL  6         // conv3 split-K parts (512x5 + 448)

__device__ __forceinline__ u16 f2bf(float f) {
  u32 u = __float_as_uint(f);
  u32 r = (u + 0x7fffu + ((u >> 16) & 1u)) >> 16;  // RNE
  return (u16)r;
}

// async global->LDS 16B copy; LDS dest = wave-uniform base + lane*16.
// NOTE (R6 post-mortem): NEVER pass a nonzero `offset` param — for LDS-DMA the
// instruction offset is applied to the LDS WRITE address (M0+offset+lane*size),
// not the global address. R6's offset=64 staged half-1 from the wrong source
// into shifted LDS slots -> deterministic garbage (absmax 468 signature).
// Express global offsets via explicit pointer arithmetic instead.
__device__ __forceinline__ void cp16(const void* g, void* l) {
  __builtin_amdgcn_global_load_lds((const __attribute__((address_space(1))) void*)g,
                                   (__attribute__((address_space(3))) void*)l, 16, 0, 0);
}

// XCD-aware chunked remap; bijective iff nwg % 8 == 0 (all our grids are).
__device__ __forceinline__ int xcd_remap(int flat, int nwg) {
  return (flat & 7) * (nwg >> 3) + (flat >> 3);
}

// ================== shared MFMA K-loop core ==================
// 128x128 tile, BK=64 via two stacked 128x32 halves, 256 threads, 32 KB LDS.
// Single-buffer + 2 barriers per 64-K. Half 1 staged from the SAME pointers
// +32 elements (explicit address math, offset param always 0 — see cp16 note).
// XOR-swizzled chunk columns at staging keep ds_read_b128 conflict-free.
// Staging swizzle (per 32-half): LDS slot (row, ch) holds global chunk
// (row, ch ^ ((row>>1)&3)).
// NOTE (R3): keep epilogues REGISTER-LEAN (VGPR 64->72 cost 28% occupancy).
// NOTE (R7): BK=64 costs VGPR 64->80 but nets -9% — barrier halving wins.
// NOTE (R8): do NOT split big MMA launches — same-stream kernels serialize;
// two 792-block halves cost +58us in ramp+tail vs one 1584-block launch.
#define MMA_PROLOGUE                                                                   \
  __shared__ alignas(16) u16 As0[8192], Bs0[8192];                                     \
  int tid = threadIdx.x;                                                               \
  int lane = tid & 63, wave = tid >> 6, wm = wave >> 1, wn = wave & 1;                 \
  f32x4 acc[4][4];                                                                     \
  _Pragma("unroll")                                                                    \
  for (int i = 0; i < 4; ++i)                                                          \
    _Pragma("unroll")                                                                  \
    for (int j = 0; j < 4; ++j) acc[i][j] = (f32x4){0.f, 0.f, 0.f, 0.f};               \
  int c0 = tid, c1 = tid + 256;                                                        \
  int r0 = c0 >> 2, r1 = c1 >> 2;                                                      \
  int s0 = (c0 & 3) ^ ((r0 >> 1) & 3);                                                 \
  int s1 = (c1 & 3) ^ ((r1 >> 1) & 3);                                                 \
  int wofs = wave * 512;                                                               \
  int rsel = lane & 15;                                                                \
  int sc   = ((lane >> 4) ^ ((rsel >> 1) & 3)) * 8;                                    \
  int aro  = (wm * 64 + rsel) * 32 + sc;                                               \
  int bro  = (wn * 64 + rsel) * 32 + sc;

#define MMA_LIN_AB(PA, PB, KpadV)                                                      \
  const u16* gA0 = (PA) + (size_t)r0 * (KpadV) + s0 * 8;                               \
  const u16* gB0 = (PB) + (size_t)r0 * (KpadV) + s0 * 8;                               \
  const u16* gA1 = (PA) + (size_t)r1 * (KpadV) + s1 * 8;                               \
  const u16* gB1 = (PB) + (size_t)r1 * (KpadV) + s1 * 8;

#define MMA_HALF(H)                                                                    \
  {                                                                                    \
    bf16x8 af[4], bfr[4];                                                              \
    _Pragma("unroll")                                                                  \
    for (int m = 0; m < 4; ++m) {                                                      \
      af[m]  = *(const bf16x8*)(const void*)(As0 + (H) * 4096 + aro + m * 512);        \
      bfr[m] = *(const bf16x8*)(const void*)(Bs0 + (H) * 4096 + bro + m * 512);        \
    }                                                                                  \
    _Pragma("unroll")                                                                  \
    for (int mi = 0; mi < 4; ++mi)                                                     \
      _Pragma("unroll")                                                                \
      for (int mj = 0; mj < 4; ++mj)                                                   \
        acc[mi][mj] = __builtin_amdgcn_mfma_f32_16x16x32_bf16(af[mi], bfr[mj],         \
                                                              acc[mi][mj], 0, 0, 0);   \
  }

#define MMA_LOOP(kBegV, kEndV)                                                         \
  for (int kk = (kBegV); kk < (kEndV); kk += 64) {                                     \
    const u16* a0 = gA0 + kk;  const u16* b0 = gB0 + kk;                               \
    const u16* a1 = gA1 + kk;  const u16* b1 = gB1 + kk;                               \
    cp16(a0, As0 + wofs);             cp16(b0, Bs0 + wofs);                            \
    cp16(a1, As0 + 2048 + wofs);      cp16(b1, Bs0 + 2048 + wofs);                     \
    cp16(a0 + 32, As0 + 4096 + wofs); cp16(b0 + 32, Bs0 + 4096 + wofs);                \
    cp16(a1 + 32, As0 + 6144 + wofs); cp16(b1 + 32, Bs0 + 6144 + wofs);                \
    __syncthreads();                                                                   \
    MMA_HALF(0)                                                                        \
    MMA_HALF(1)                                                                        \
    __syncthreads();                                                                   \
  }

// ---------------- fused pad+convert of conv weights (+ zero BN accumulators) ----------------
// Aw1/Aw2 reordered to [co][kf] with kf = k*300 + ci (k-major) so that the
// im2col row is a CONTIGUOUS slice of the [b][pos][chan] activation buffer.
// Columns kf in [1500,1536) are ZERO => window over-reads are annihilated.
__global__ void wconv_k(const float* __restrict__ w1, const float* __restrict__ w2,
                        const float* __restrict__ w3, u16* __restrict__ Aw1,
                        u16* __restrict__ Aw2, u16* __restrict__ Aw3,
                        float* __restrict__ bnAcc) {
  if (blockIdx.x == 0) {  // re-zero BN partial-sum accumulators every replay
    for (int i = threadIdx.x; i < 1800; i += 256) bnAcc[i] = 0.f;
  }
  int idx = blockIdx.x * 256 + threadIdx.x;
  const int t1 = 384 * KP1, t2 = 640 * KP1, t3 = 128 * KP3;
  if (idx < t1) {
    int m = idx / KP1, kf = idx - m * KP1;
    u16 v = 0;
    if (m < 300 && kf < 1500) { int k = kf / 300, ci = kf - k * 300; v = f2bf(w1[m * 1500 + ci * 5 + k]); }
    Aw1[idx] = v;
  } else if ((idx -= t1) < t2) {
    int m = idx / KP1, kf = idx - m * KP1;
    u16 v = 0;
    if (m < 600 && kf < 1500) { int k = kf / 300, ci = kf - k * 300; v = f2bf(w2[m * 1500 + ci * 5 + k]); }
    Aw2[idx] = v;
  } else if ((idx -= t2) < t3) {
    int m = idx / KP3, k = idx - m * KP3;
    Aw3[idx] = (m < 100 && k < 3000) ? f2bf(w3[m * 3000 + k]) : (u16)0;
  }
}

// ---------------- embedding row scales: min(1, 1/(||row||+1e-7)) ----------------
__global__ __launch_bounds__(256) void scale_k(const float* __restrict__ emb,
                                               float* __restrict__ scale) {
  int r = blockIdx.x * 4 + (threadIdx.x >> 6);
  int lane = threadIdx.x & 63;
  const float* row = emb + (size_t)r * DEMB;
  float s = 0.f;
  for (int d = lane; d < DEMB; d += 64) { float v = row[d]; s += v * v; }
  for (int off = 32; off; off >>= 1) s += __shfl_xor(s, off, 64);
  if (lane == 0) scale[r] = fminf(1.f, 1.f / (sqrtf(s) + 1e-7f));
}

// ---------------- gather -> Xl bf16 [4096][8768], layout k = (l+1)*300 + d ----------------
// Position 0 (k in [0,300)) is zeros = the pad=1 column; tail [8700,8768) zeros.
__global__ __launch_bounds__(256) void embed_k(const int* __restrict__ x,
                                               const float* __restrict__ emb,
                                               const float* __restrict__ scale,
                                               u16* __restrict__ Xl) {
  __shared__ alignas(16) u16 es[KPAD];
  int b = blockIdx.x, tid = threadIdx.x;
  for (int i = tid; i < 300; i += 256) es[i] = 0;   // pad-position block (loop, not guard!)
  if (tid < 68) es[8700 + tid] = 0;                 // K tail zeros
  const int* xr = x + b * LSEQ;
  for (int l = 0; l < LSEQ; ++l) {
    int v = xr[l];
    float s = scale[v];
    const float* er = emb + (size_t)v * DEMB;
    for (int d = tid; d < DEMB; d += 256) es[(l + 1) * 300 + d] = f2bf(er[d] * s);
  }
  __syncthreads();
  uint4* dst = (uint4*)(Xl + (size_t)b * KPAD);
  const uint4* s4 = (const uint4*)es;
  for (int i = tid; i < KPAD / 8; i += 256) dst[i] = s4[i];
}

// ---------------- BN partial stats: grid C*parts blocks, contiguous chunks ----------------
// 1200 blocks (vs 300/600 single-pass = latency-starved); one atomicAdd pair
// per block into bnAcc (zeroed by wconv). R8: -~50us combined with G3SPL=6.
__global__ __launch_bounds__(256) void statsp_k(const float* __restrict__ src, int Ntot,
                                                int parts, float* __restrict__ sumP,
                                                float* __restrict__ sqP) {
  int c = blockIdx.x / parts, part = blockIdx.x - c * parts;
  int chunk = Ntot / parts;   // 53248/4=13312, 20480/2=10240 — both exact
  const float* rp = src + (size_t)c * Ntot + part * chunk;
  float s = 0.f, sq = 0.f;
  for (int i = threadIdx.x; i < chunk; i += 256) { float v = rp[i]; s += v; sq += v * v; }
  for (int off = 32; off; off >>= 1) { s += __shfl_xor(s, off, 64); sq += __shfl_xor(sq, off, 64); }
  __shared__ float l1[4], l2[4];
  int wave = threadIdx.x >> 6, lane = threadIdx.x & 63;
  if (lane == 0) { l1[wave] = s; l2[wave] = sq; }
  __syncthreads();
  if (threadIdx.x == 0) {
    atomicAdd(&sumP[c], l1[0] + l1[1] + l1[2] + l1[3]);
    atomicAdd(&sqP[c],  l2[0] + l2[1] + l2[2] + l2[3]);
  }
}

// ---------------- bn1+relu(C1) -> Y bf16 [4096][3968], layout k = p*300 + ci ----------------
// BN finalize INLINED (R9: drops a 2-block finstats launch; identical arithmetic
// incl. division -> bit-identical). XCD-clustered b: adjacent b read the SAME
// C1 cache lines (52B apart) -> one L2.
__global__ __launch_bounds__(256) void y2_k(const float* __restrict__ C1,
                                            const float* __restrict__ sum,
                                            const float* __restrict__ sq,
                                            const float* __restrict__ g,
                                            const float* __restrict__ be,
                                            u16* __restrict__ Y) {
  int b = xcd_remap(blockIdx.x, NB), tid = threadIdx.x;
  u16* yr = Y + (size_t)b * YSTR;
  for (int i = tid; i < YSTR; i += 256) {
    u16 v = 0;
    if (i < 3900) {
      int t = i / 300, ci = i - t * 300;
      float mean = sum[ci] / N1TOT;
      float var  = sq[ci] / N1TOT - mean * mean;
      float A = g[ci] * rsqrtf(var + 1e-5f);
      float Bv = be[ci] - mean * A;
      v = f2bf(fmaxf(0.f, fmaf(C1[(size_t)ci * N1TOT + b * 13 + t], A, Bv)));
    }
    yr[i] = v;
  }
}

// ---------------- im2col for conv3: bn2+relu(C2) -> X3 [4096][3008] ----------------
// BN finalize inlined (R9). XCD-clustered b (C2 column reads, 20B apart).
__global__ __launch_bounds__(128) void im2col3_k(const float* __restrict__ C2,
                                                 const float* __restrict__ sum,
                                                 const float* __restrict__ sq,
                                                 const float* __restrict__ g,
                                                 const float* __restrict__ be,
                                                 u16* __restrict__ X3) {
  int b = xcd_remap(blockIdx.x, NB), tid = threadIdx.x;
  for (int c = tid; c < 376; c += 128) {
    uint4 v;
    u32 wv[4];
    #pragma unroll
    for (int jj = 0; jj < 4; ++jj) {
      u32 pk = 0;
      #pragma unroll
      for (int h = 0; h < 2; ++h) {
        int idx = c * 8 + jj * 2 + h;
        u16 e = 0;
        if (idx < 3000) {
          int ci = idx / 5, k = idx - ci * 5;
          float mean = sum[ci] / N2TOT;
          float var  = sq[ci] / N2TOT - mean * mean;
          float A = g[ci] * rsqrtf(var + 1e-5f);
          float Bv = be[ci] - mean * A;
          float val = fmaxf(0.f, fmaf(C2[(size_t)ci * N2TOT + b * 5 + k], A, Bv));
          e = f2bf(val);
        }
        pk |= ((u32)e) << (16 * h);
      }
      wv[jj] = pk;
    }
    v.x = wv[0]; v.y = wv[1]; v.z = wv[2]; v.w = wv[3];
    *(uint4*)(X3 + (size_t)b * KP3 + c * 8) = v;
  }
}

// ---------------- conv GEMM, implicit im2col: C = Aw . window-slices(X)^T ----------------
// B row n -> (b = n/NT, t = n%NT); slice base = b*rowStride + 600*t (16B-aligned).
// R9: tm-FASTEST enumeration (tm = orig % gridDim.y) so each XCD owns a
// contiguous tn-range with ALL tm -> each B-panel fetched into ONE L2 (was 3-5x).
__global__ __launch_bounds__(256) void cgemm_k(const u16* __restrict__ A,
                                               const u16* __restrict__ X,
                                               int rowStride, int NT, int Kpad,
                                               int M, int NtotC, float* __restrict__ C) {
  MMA_PROLOGUE
  int flat = blockIdx.y * gridDim.x + blockIdx.x;
  int orig = xcd_remap(flat, gridDim.x * gridDim.y);
  int tm = orig % gridDim.y, tn = orig / gridDim.y;
  const u16* PA  = A + (size_t)(tm * 128) * Kpad;
  const u16* gA0 = PA + (size_t)r0 * Kpad + s0 * 8;
  const u16* gA1 = PA + (size_t)r1 * Kpad + s1 * 8;
  int n0g = tn * 128 + r0, n1g = tn * 128 + r1;
  int b0 = n0g / NT, b1 = n1g / NT;
  const u16* gB0 = X + (size_t)b0 * rowStride + 600 * (n0g - b0 * NT) + s0 * 8;
  const u16* gB1 = X + (size_t)b1 * rowStride + 600 * (n1g - b1 * NT) + s1 * 8;
  MMA_LOOP(0, Kpad)

  int rb = wm * 64 + ((lane >> 4) << 2);
  int cb = wn * 64 + (lane & 15);
  #pragma unroll
  for (int mi = 0; mi < 4; ++mi)
    #pragma unroll
    for (int r = 0; r < 4; ++r) {
      int m = tm * 128 + rb + mi * 16 + r;
      if (m < M) {
        float* crow = C + (size_t)m * NtotC + tn * 128 + cb;
        #pragma unroll
        for (int mj = 0; mj < 4; ++mj) crow[mj * 16] = acc[mi][mj][r];
      }
    }
}

// ---------------- conv3 partial GEMM, split-K=6 (512x5+448): Ph[(s*32+tn)][m*128+n] ----------------
__global__ __launch_bounds__(256) void gemm3p_k(const u16* __restrict__ A,
                                                const u16* __restrict__ B,
                                                float* __restrict__ Ph) {
  MMA_PROLOGUE
  int tn = blockIdx.x, s = blockIdx.y;
  int kBeg = s * 512;
  int kEnd = (s == G3SPL - 1) ? KP3 : kBeg + 512;
  const u16* PA = A;
  const u16* PB = B + (size_t)(tn * 128) * KP3;
  MMA_LIN_AB(PA, PB, KP3)
  MMA_LOOP(kBeg, kEnd)

  float* po = Ph + ((size_t)(s * 32 + tn)) * 16384;
  int rb = wm * 64 + ((lane >> 4) << 2);
  int cb = wn * 64 + (lane & 15);
  #pragma unroll
  for (int mi = 0; mi < 4; ++mi)
    #pragma unroll
    for (int r = 0; r < 4; ++r) {
      int m = rb + mi * 16 + r;
      #pragma unroll
      for (int mj = 0; mj < 4; ++mj) po[(size_t)m * 128 + cb + mj * 16] = acc[mi][mj][r];
    }
}

// ---------------- finalize conv3: sum partials + bias, tanh, write h, normalize -> Fn ----------------
__global__ __launch_bounds__(64) void fin_k(const float* __restrict__ Ph,
                                            const float* __restrict__ b3,
                                            float* __restrict__ out, u16* __restrict__ Fn) {
  int b = xcd_remap(blockIdx.x, NB), lane = threadIdx.x;
  int tn = b >> 7, bl = b & 127;
  const float* base = Ph + (size_t)tn * 16384 + bl;
  float v0 = b3[lane];
  #pragma unroll
  for (int s = 0; s < G3SPL; ++s) v0 += base[(size_t)s * 32 * 16384 + lane * 128];
  v0 = tanhf(v0);
  float v1 = 0.f;
  if (lane + 64 < 100) {
    v1 = b3[lane + 64];
    #pragma unroll
    for (int s = 0; s < G3SPL; ++s) v1 += base[(size_t)s * 32 * 16384 + (lane + 64) * 128];
    v1 = tanhf(v1);
  }
  float s = v0 * v0 + v1 * v1;
  for (int off = 32; off; off >>= 1) s += __shfl_xor(s, off, 64);
  float rn = rsqrtf(s);
  out[(size_t)b * 100 + lane] = v0;
  if (lane + 64 < 100) out[(size_t)b * 100 + lane + 64] = v1;
  u16* orow = Fn + (size_t)b * 128;
  orow[lane]      = f2bf(v0 * rn);
  orow[lane + 64] = (lane + 64 < 100) ? f2bf(v1 * rn) : (u16)0;
}

// ---------------- input gram, split-K over REAL data [256,8704) = 3 x 44 x 64 ----------------
// R9: trimmed the zero pad-position block [0,256) and tail [8704,8768) from K
// (zeros contribute nothing to dot products) — 137 -> 132 BK-blocks, -3.6%.
// ONE 1584-block launch (R8: splitting into two 792-block launches cost +58us).
__global__ __launch_bounds__(256) void gram_part_k(const u16* __restrict__ P,
                                                   float* __restrict__ Pout) {
  MMA_PROLOGUE
  int flat = blockIdx.y * 528 + blockIdx.x;
  int orig = xcd_remap(flat, 528 * GSPLIT);
  int s = orig / 528, tile = orig - s * 528;
  int q = tile, ti = 0;
  while (q >= 32 - ti) { q -= 32 - ti; ++ti; }
  int tj = ti + q;
  int kBeg = 256 + s * 2816;
  int kEnd = kBeg + 2816;
  const u16* PA = P + (size_t)ti * 128 * KPAD;
  const u16* PB = P + (size_t)tj * 128 * KPAD;
  MMA_LIN_AB(PA, PB, KPAD)
  MMA_LOOP(kBeg, kEnd)

  float* po = Pout + ((size_t)(s * 528 + tile)) * 16384;
  int rb = wm * 64 + ((lane >> 4) << 2);
  int cb = wn * 64 + (lane & 15);
  #pragma unroll
  for (int mi = 0; mi < 4; ++mi)
    #pragma unroll
    for (int r = 0; r < 4; ++r) {
      int row = rb + mi * 16 + r;
      #pragma unroll
      for (int mj = 0; mj < 4; ++mj) po[(size_t)row * 128 + cb + mj * 16] = acc[mi][mj][r];
    }
}

// ---------------- reduce split-K partials -> triangular pair list ----------------
__global__ __launch_bounds__(256) void reduce_k(const float* __restrict__ P,
                                                float* __restrict__ outp) {
  int tile = blockIdx.x;
  int q = tile, ti = 0;
  while (q >= 32 - ti) { q -= 32 - ti; ++ti; }
  int tj = ti + q;
  const float4* p0 = (const float4*)(P + (size_t)tile * 16384);
  const float4* p1 = (const float4*)(P + (size_t)(528 + tile) * 16384);
  const float4* p2 = (const float4*)(P + (size_t)(1056 + tile) * 16384);
  for (int e = threadIdx.x; e < 4096; e += 256) {
    float4 a = p0[e], bv = p1[e], cv = p2[e];
    int i = e >> 5;
    int j0 = (e & 31) * 4;
    int gi = ti * 128 + i;
    int gj = tj * 128 + j0;
    float v[4] = {a.x + bv.x + cv.x, a.y + bv.y + cv.y,
                  a.z + bv.z + cv.z, a.w + bv.w + cv.w};
    #pragma unroll
    for (int u = 0; u < 4; ++u) {
      int gjj = gj + u;
      if (gi < gjj) {
        int pidx = gi * (NB - 1) - ((gi * (gi - 1)) >> 1) + (gjj - gi - 1);
        outp[pidx] = v[u];
      }
    }
  }
}

// ---------------- direct triangular gram (for hidden, K=128) ----------------
__global__ __launch_bounds__(256) void gram_k(const u16* __restrict__ P, int Kpad,
                                              float* __restrict__ outp) {
  MMA_PROLOGUE
  int q = blockIdx.x, ti = 0;
  while (q >= 32 - ti) { q -= 32 - ti; ++ti; }
  int tj = ti + q;
  const u16* PA = P + (size_t)ti * 128 * Kpad;
  const u16* PB = P + (size_t)tj * 128 * Kpad;
  MMA_LIN_AB(PA, PB, Kpad)
  MMA_LOOP(0, Kpad)

  int rbase = ti * 128 + wm * 64 + ((lane >> 4) << 2);
  int cbase = tj * 128 + wn * 64 + (lane & 15);
  #pragma unroll
  for (int mi = 0; mi < 4; ++mi)
    #pragma unroll
    for (int mj = 0; mj < 4; ++mj) {
      int gj = cbase + mj * 16;
      #pragma unroll
      for (int r = 0; r < 4; ++r) {
        int gi = rbase + mi * 16 + r;
        if (gi < gj) {
          int p = gi * (NB - 1) - ((gi * (gi - 1)) >> 1) + (gj - gi - 1);
          outp[p] = acc[mi][mj][r];
        }
      }
    }
}

extern "C" void kernel_launch(void* const* d_in, const int* in_sizes, int n_in,
                              void* d_out, int out_size, void* d_ws, size_t ws_size,
                              hipStream_t stream) {
  const int*   x   = (const int*)d_in[0];
  const float* emb = (const float*)d_in[1];
  const float* w1  = (const float*)d_in[2];
  const float* w2  = (const float*)d_in[4];
  const float* w3  = (const float*)d_in[6];
  const float* b3  = (const float*)d_in[7];
  const float* g1  = (const float*)d_in[8];
  const float* be1 = (const float*)d_in[9];
  const float* g2  = (const float*)d_in[10];
  const float* be2 = (const float*)d_in[11];
  float* out = (float*)d_out;

  char* p = (char*)d_ws;
  auto alloc = [&](size_t bytes) { char* r = p; p += (bytes + 255) & ~(size_t)255; return r; };
  float* scale = (float*)alloc((size_t)32000 * 4);
  u16*   Aw1   = (u16*)alloc((size_t)384 * KP1 * 2);
  u16*   Aw2   = (u16*)alloc((size_t)640 * KP1 * 2);
  u16*   Aw3   = (u16*)alloc((size_t)128 * KP3 * 2);
  float* bnAcc = (float*)alloc(1800 * 4);   // sum1[300] sq1[300] sum2[600] sq2[600]
  float* sum1 = bnAcc, *sq1 = bnAcc + 300, *sum2 = bnAcc + 600, *sq2 = bnAcc + 1200;
  u16*   Fn    = (u16*)alloc((size_t)NB * 128 * 2);
  // Region 1 (71.8MB): Xl -> Y -> X3 (each producer runs after prior consumer)
  char*  reg1  = alloc((size_t)NB * KPAD * 2);
  // Region 2 (103.8MB): Pg -> C1 -> C2 -> Ph
  char*  reg2  = alloc((size_t)GSPLIT * 528 * 16384 * 4);
  u16*   Xl = (u16*)reg1;
  u16*   Y  = (u16*)reg1;
  u16*   X3 = (u16*)reg1;
  float* Pg = (float*)reg2;
  float* C1 = (float*)reg2;
  float* C2 = (float*)reg2;
  float* Ph = (float*)reg2;

  wconv_k<<<(384 * KP1 + 640 * KP1 + 128 * KP3 + 255) / 256, 256, 0, stream>>>(
      w1, w2, w3, Aw1, Aw2, Aw3, bnAcc);
  scale_k<<<32000 / 4, 256, 0, stream>>>(emb, scale);
  embed_k<<<NB, 256, 0, stream>>>(x, emb, scale, Xl);

  // input_pws: split-K gram (1584 blocks, XCD-chunked) + reduction
  gram_part_k<<<dim3(528, GSPLIT), 256, 0, stream>>>(Xl, Pg);
  reduce_k<<<528, 256, 0, stream>>>(Pg, out + 409600);

  // conv1: implicit-im2col GEMM straight from Xl (Pg dead; C1 -> reg2)
  cgemm_k<<<dim3(416, 3), 256, 0, stream>>>(Aw1, Xl, KPAD, 13, KP1, 300, N1TOT, C1);
  statsp_k<<<300 * 4, 256, 0, stream>>>(C1, N1TOT, 4, sum1, sq1);
  y2_k<<<NB, 256, 0, stream>>>(C1, sum1, sq1, g1, be1, Y);             // Y over Xl (dead)
  // conv2: implicit-im2col GEMM from Y (C2 over C1, dead)
  cgemm_k<<<dim3(160, 5), 256, 0, stream>>>(Aw2, Y, YSTR, 5, KP1, 600, N2TOT, C2);
  statsp_k<<<600 * 2, 256, 0, stream>>>(C2, N2TOT, 2, sum2, sq2);
  im2col3_k<<<NB, 128, 0, stream>>>(C2, sum2, sq2, g2, be2, X3);       // X3 over Y (dead)
  gemm3p_k<<<dim3(32, G3SPL), 256, 0, stream>>>(Aw3, X3, Ph);          // conv3 split-K=6
  fin_k<<<NB, 64, 0, stream>>>(Ph, b3, out, Fn);                       // h + normalized Fn
  gram_k<<<528, 256, 0, stream>>>(Fn, 128, out + 409600 + NPAIRS);     // hidden_pws
}